// Round 9
// baseline (793.369 us; speedup 1.0000x reference)
//
#include <hip/hip_runtime.h>
#include <math.h>

// DCGRU cell, N=4096, B=32, U=64, F=66, M=5, 2 supports.
// R9: SpMM async-LDS gather with ONE global_load_lds size=16 per nnz (1 KB
// full-wave DMA; R8 paid 2 DMAs + 6 VALU addr per 512 B). 4 panels x 1 KB,
// XCD pin bx&3 (mirrored pairs). 128-thread blocks, 2x8-nnz wave-private
// buffers (32 KB -> 5 blk/CU), scalar val prefetch, NT streams. Cheb singles;
// hop1 shared-source pair; xi tails + gconv2 xi reuse (R8). MFMA gate/cand.

#define NN 4096
#define BB 32
#define UU 64
#define FF 66
#define MM 5
#define XHC 2048       // xh row elements (4096 B)
#define XIC 64         // xi row elements (128 B)
#define CAP 128        // max nnz/row, padded to %8 (min 16)
#define KPAD 360
#define KSTEPS 11
#define CHUNK 8
#define WF_G (8*11*64*8)
#define WF_C (4*11*64*8)

typedef unsigned short u16;
typedef __attribute__((ext_vector_type(8))) short short8;
typedef __attribute__((ext_vector_type(4))) float float4v;

__device__ __forceinline__ u16 f2bf(float f) {
  unsigned u = __float_as_uint(f);
  u += 0x7FFFu + ((u >> 16) & 1u);   // RNE
  return (u16)(u >> 16);
}
__device__ __forceinline__ unsigned pack2(float lo, float hi) {
  return (unsigned)f2bf(lo) | ((unsigned)f2bf(hi) << 16);
}
__device__ __forceinline__ float bflo(unsigned d) { return __uint_as_float(d << 16); }
__device__ __forceinline__ float bfhi(unsigned d) { return __uint_as_float(d & 0xFFFF0000u); }
__device__ __forceinline__ float bf1(u16 v) { return __uint_as_float((unsigned)v << 16); }

__device__ __forceinline__ float sigmoidf_(float x) {
  return 1.0f / (1.0f + __expf(-x));
}
__device__ __forceinline__ float tanhf_(float x) {
  x = fminf(fmaxf(x, -15.f), 15.f);
  float e = __expf(2.f * x);
  return (e - 1.f) / (e + 1.f);
}

// ---------------- CSR extraction: rows zero-padded to %8, min 16 ------------
__global__ __launch_bounds__(256) void extract_csr(
    const float* __restrict__ S0, const float* __restrict__ S1,
    int* __restrict__ cols, float* __restrict__ vals, int* __restrict__ nnz) {
  int wave = threadIdx.x >> 6;
  int lane = threadIdx.x & 63;
  int row  = blockIdx.x * 4 + wave;
  int sup  = blockIdx.y;
  const float* srow = (sup ? S1 : S0) + (size_t)row * NN;
  int*   crow = cols + ((size_t)sup * NN + row) * CAP;
  float* vrow = vals + ((size_t)sup * NN + row) * CAP;
  int base = 0;
  for (int j0 = 0; j0 < NN; j0 += 64) {
    float v = srow[j0 + lane];
    unsigned long long mask = __ballot(v != 0.0f);
    if (v != 0.0f) {
      int pos = base + __popcll(mask & ((1ull << lane) - 1ull));
      if (pos < CAP) { crow[pos] = j0 + lane; vrow[pos] = v; }
    }
    base += __popcll(mask);
  }
  if (base > CAP) base = CAP;
  int padded = (base + 7) & ~7;
  if (padded < 16) padded = 16;
  if (padded > CAP) padded = CAP;
  int p = base + lane;
  if (p < padded) { crow[p] = 0; vrow[p] = 0.0f; }
  if (lane == 0) nnz[sup * NN + row] = padded;
}

// ---------------- weight prep: W -> MFMA B-fragment order --------------------
__global__ __launch_bounds__(256) void prep_w(
    const float* __restrict__ W, const float* __restrict__ W2,
    u16* __restrict__ Wf, u16* __restrict__ W2f) {
  int idx = blockIdx.x * 256 + threadIdx.x;
  if (idx < WF_G) {
    int j = idx & 7, lane = (idx >> 3) & 63, q = idx >> 9;
    int ks = q % 11, t = q / 11;
    int k = ks * 32 + (lane >> 4) * 8 + j, o = t * 16 + (lane & 15);
    float v = 0.f;
    if (k < 330) { int m = k / FF, f = k - m * FF; v = W[((size_t)f * MM + m) * 128 + o]; }
    Wf[idx] = f2bf(v);
  } else if (idx < WF_G + WF_C) {
    int i2 = idx - WF_G;
    int j = i2 & 7, lane = (i2 >> 3) & 63, q = i2 >> 9;
    int ks = q % 11, t = q / 11;
    int k = ks * 32 + (lane >> 4) * 8 + j, o = t * 16 + (lane & 15);
    float v = 0.f;
    if (k < 330) { int m = k / FF, f = k - m * FF; v = W2[((size_t)f * MM + m) * UU + o]; }
    W2f[i2] = f2bf(v);
  }
}

// ---------------- build xi0 / xh0 -------------------------------------------
__global__ __launch_bounds__(256) void build_x0(
    const float* __restrict__ inp, const float* __restrict__ hx,
    u16* __restrict__ xi0, u16* __restrict__ xh0) {
  int n = blockIdx.x;
  unsigned* xhd = (unsigned*)(xh0 + (size_t)n * XHC);
  for (int j = threadIdx.x; j < XHC / 2; j += 256) {
    int b = j >> 5, f2 = (j & 31) * 2;
    const float* h = hx + (size_t)b * (NN * UU) + (size_t)n * UU + f2;
    xhd[j] = pack2(h[0], h[1]);
  }
  if (threadIdx.x < 32) {
    int b = threadIdx.x;
    unsigned* xid = (unsigned*)(xi0 + (size_t)n * XIC);
    xid[b] = pack2(inp[(size_t)b * (NN * 2) + n * 2],
                   inp[(size_t)b * (NN * 2) + n * 2 + 1]);
  }
}

// ---------------- SpMM: 4 x 1 KB panels, 1 DMA/nnz, 2-wave blocks -----------
__device__ __forceinline__ void fma8(float v, uint4 q, float* a) {
  a[0] = fmaf(v, bflo(q.x), a[0]); a[1] = fmaf(v, bfhi(q.x), a[1]);
  a[2] = fmaf(v, bflo(q.y), a[2]); a[3] = fmaf(v, bfhi(q.y), a[3]);
  a[4] = fmaf(v, bflo(q.z), a[4]); a[5] = fmaf(v, bfhi(q.z), a[5]);
  a[6] = fmaf(v, bflo(q.w), a[6]); a[7] = fmaf(v, bfhi(q.w), a[7]);
}

// issue CHUNK nnz: one 1 KB full-wave DMA each (lane scatter = lane*16 B)
__device__ __forceinline__ void issueC(
    u16* buf, const int* crow, int k0, const u16* gpan, int lane) {
#pragma unroll
  for (int i = 0; i < CHUNK; ++i) {
    int c = crow[k0 + i];                               // scalar (s_load)
    const u16* g = gpan + ((size_t)c << 11) + (lane << 3);
    __builtin_amdgcn_global_load_lds(
        (const __attribute__((address_space(1))) void*)g,
        (__attribute__((address_space(3))) void*)(buf + i * 512), 16, 0, 0);
  }
}

__global__ __launch_bounds__(128) void spmm_panel(
    const int* __restrict__ cols, const float* __restrict__ vals,
    const int* __restrict__ nnz,
    const u16* xiA, const u16* xhA, const u16* xiB, const u16* xhB,
    const u16* zi, const u16* zh,
    float alpha, float beta, int sup_base,
    u16* yiA, u16* yhA, u16* yiB, u16* yhB) {
  __shared__ u16 stage[2 * 2 * CHUNK * 512];   // 2 waves x 2 bufs x 8 KB
  int bx = blockIdx.x;
  int lane = threadIdx.x & 63;
  int wv = threadIdx.x >> 6;                   // 0..1
  int sup = sup_base + blockIdx.y;

  if (bx < 8192) {
    // ---- xh path ----
    int panel = bx & 3;
    int row = (bx >> 2) * 2 + wv;
    int srow = __builtin_amdgcn_readfirstlane(sup * NN + row);
    const u16* xh = blockIdx.y ? xhB : xhA;
    u16* yh = blockIdx.y ? yhB : yhA;
    const int*   crow = cols + (size_t)srow * CAP;
    const float* vrow = vals + (size_t)srow * CAP;
    int cnt = nnz[srow];                       // %8, >=16
    int nch = cnt >> 3;                        // >=2
    u16* st = stage + wv * (2 * CHUNK * 512);
    const u16* gpan = xh + panel * 512;
    float a[8] = {0.f,0.f,0.f,0.f,0.f,0.f,0.f,0.f};

    issueC(st,               crow, 0,     gpan, lane);
    issueC(st + CHUNK * 512, crow, CHUNK, gpan, lane);
    float vv[CHUNK];
#pragma unroll
    for (int i = 0; i < CHUNK; ++i) vv[i] = vrow[i];

    for (int c = 0; c < nch; ++c) {
      float vvn[CHUNK];
      if (c + 1 < nch) {
#pragma unroll
        for (int i = 0; i < CHUNK; ++i) vvn[i] = vrow[(c + 1) * CHUNK + i];
      }
      if (c < nch - 1) asm volatile("s_waitcnt vmcnt(8)" ::: "memory");
      else             asm volatile("s_waitcnt vmcnt(0)" ::: "memory");
      u16* buf = st + (c & 1) * (CHUNK * 512);
#pragma unroll
      for (int i = 0; i < CHUNK; ++i) {
        uint4 q = *(const uint4*)(buf + i * 512 + lane * 8);
        fma8(vv[i], q, a);
      }
      if (c + 2 < nch) issueC(buf, crow, (c + 2) * CHUNK, gpan, lane);
#pragma unroll
      for (int i = 0; i < CHUNK; ++i) vv[i] = vvn[i];
    }

    size_t oh = (size_t)row * XHC + panel * 512 + lane * 8;
    float r[8];
#pragma unroll
    for (int j = 0; j < 8; ++j) r[j] = alpha * a[j];
    if (zh) {
      uint4 zq;
      zq.x = __builtin_nontemporal_load((const unsigned*)(zh + oh));
      zq.y = __builtin_nontemporal_load((const unsigned*)(zh + oh) + 1);
      zq.z = __builtin_nontemporal_load((const unsigned*)(zh + oh) + 2);
      zq.w = __builtin_nontemporal_load((const unsigned*)(zh + oh) + 3);
      r[0] += beta * bflo(zq.x); r[1] += beta * bfhi(zq.x);
      r[2] += beta * bflo(zq.y); r[3] += beta * bfhi(zq.y);
      r[4] += beta * bflo(zq.z); r[5] += beta * bfhi(zq.z);
      r[6] += beta * bflo(zq.w); r[7] += beta * bfhi(zq.w);
    }
    __builtin_nontemporal_store(pack2(r[0], r[1]), (unsigned*)(yh + oh));
    __builtin_nontemporal_store(pack2(r[2], r[3]), (unsigned*)(yh + oh) + 1);
    __builtin_nontemporal_store(pack2(r[4], r[5]), (unsigned*)(yh + oh) + 2);
    __builtin_nontemporal_store(pack2(r[6], r[7]), (unsigned*)(yh + oh) + 3);
  } else {
    // ---- xi path: one wave per row (128 B rows, register gather) ----
    int row = (bx - 8192) * 2 + wv;
    int srow = __builtin_amdgcn_readfirstlane(sup * NN + row);
    const u16* xs = blockIdx.y ? xiB : xiA;
    u16* yo = blockIdx.y ? yiB : yiA;
    const int*   crow = cols + (size_t)srow * CAP;
    const float* vrow = vals + (size_t)srow * CAP;
    int cnt = nnz[srow];
    float a = 0.f;
    for (int k0 = 0; k0 < cnt; k0 += 8) {
      int cc[8]; float vv[8];
#pragma unroll
      for (int i = 0; i < 8; ++i) { cc[i] = crow[k0 + i]; vv[i] = vrow[k0 + i]; }
      u16 q[8];
#pragma unroll
      for (int i = 0; i < 8; ++i) q[i] = xs[(size_t)cc[i] * XIC + lane];
#pragma unroll
      for (int i = 0; i < 8; ++i) a = fmaf(vv[i], bf1(q[i]), a);
    }
    float r = alpha * a;
    if (zi) r += beta * bf1(zi[(size_t)row * XIC + lane]);
    yo[(size_t)row * XIC + lane] = f2bf(r);
  }
}

// ---------------- staging: 5 (xi,xh) mats -> lx[b][k=m*66+f], pad zeroed ----
__device__ __forceinline__ void stage_one(
    unsigned* lxd, int n, int m, const u16* xim, const u16* xhm) {
  const unsigned* sh = (const unsigned*)(xhm + (size_t)n * XHC);
  for (int j = threadIdx.x; j < XHC / 2; j += 256) {
    int b = j >> 5, f2d = j & 31;
    lxd[b * (KPAD / 2) + m * 33 + 1 + f2d] = sh[j];
  }
  if (threadIdx.x < 32) {
    const unsigned* si = (const unsigned*)(xim + (size_t)n * XIC);
    lxd[threadIdx.x * (KPAD / 2) + m * 33] = si[threadIdx.x];
  }
}
__device__ __forceinline__ void stage_mats(
    unsigned* lxd, int n,
    const u16* i0, const u16* i1, const u16* i2, const u16* i3, const u16* i4,
    const u16* h0, const u16* h1, const u16* h2, const u16* h3, const u16* h4) {
  stage_one(lxd, n, 0, i0, h0);
  stage_one(lxd, n, 1, i1, h1);
  stage_one(lxd, n, 2, i2, h2);
  stage_one(lxd, n, 3, i3, h3);
  stage_one(lxd, n, 4, i4, h4);
  for (int i = threadIdx.x; i < BB * 16; i += 256) {
    int b = i >> 4, d = i & 15;
    if (d < 15) lxd[b * (KPAD / 2) + 165 + d] = 0u;
  }
}

// ---------------- gate: sigmoid(x@W+bias); r*hx -> xh' (in place), u->ubuf --
__global__ __launch_bounds__(256) void gate_mfma(
    const u16* i0, const u16* __restrict__ i1, const u16* __restrict__ i2,
    const u16* __restrict__ i3, const u16* __restrict__ i4,
    const u16* h0, const u16* __restrict__ h1, const u16* __restrict__ h2,
    const u16* __restrict__ h3, const u16* __restrict__ h4,
    const u16* __restrict__ Wf, const float* __restrict__ bias,
    const float* __restrict__ hx,
    u16* xhp, float* __restrict__ ubuf) {
  __shared__ u16 lx[BB * KPAD];
  __shared__ u16 lt[BB * UU];
  int n = blockIdx.x;
  stage_mats((unsigned*)lx, n, i0, i1, i2, i3, i4, h0, h1, h2, h3, h4);
  __syncthreads();
  int lane = threadIdx.x & 63;
  int w = threadIdx.x >> 6;
  int Mtile = w & 1;
  int Nbase = (w >> 1) * 4;
  int colo = lane & 15;
  int quad = lane >> 4;
  float4v acc[4];
#pragma unroll
  for (int t = 0; t < 4; ++t) {
    float bv = bias[(Nbase + t) * 16 + colo];
    acc[t] = (float4v){bv, bv, bv, bv};
  }
  const u16* arow = &lx[(Mtile * 16 + colo) * KPAD];
  for (int ks = 0; ks < KSTEPS; ++ks) {
    short8 af = *(const short8*)(arow + ks * 32 + quad * 8);
#pragma unroll
    for (int t = 0; t < 4; ++t) {
      short8 bf = *(const short8*)(Wf + (size_t)(((Nbase + t) * KSTEPS + ks) * 64 + lane) * 8);
      acc[t] = __builtin_amdgcn_mfma_f32_16x16x32_bf16(af, bf, acc[t], 0, 0, 0);
    }
  }
  int brow0 = Mtile * 16 + quad * 4;
#pragma unroll
  for (int t = 0; t < 4; ++t) {
    int o = (Nbase + t) * 16 + colo;
#pragma unroll
    for (int r = 0; r < 4; ++r) {
      int b = brow0 + r;
      float s = sigmoidf_(acc[t][r]);
      if (o < UU) {
        float h = hx[(size_t)b * (NN * UU) + (size_t)n * UU + o];
        lt[b * UU + o] = f2bf(s * h);
      } else {
        ubuf[(size_t)n * (BB * UU) + b * UU + (o - UU)] = s;
      }
    }
  }
  __syncthreads();
  unsigned* xrow = (unsigned*)(xhp + (size_t)n * XHC);
  const unsigned* ltd = (const unsigned*)lt;
  for (int j = threadIdx.x; j < XHC / 2; j += 256)
    xrow[j] = ltd[j];
}

// ---------------- candidate + final combine ---------------------------------
__global__ __launch_bounds__(256) void cand_mfma(
    const u16* __restrict__ i0, const u16* __restrict__ i1,
    const u16* __restrict__ i2, const u16* __restrict__ i3,
    const u16* __restrict__ i4,
    const u16* __restrict__ h0, const u16* __restrict__ h1,
    const u16* __restrict__ h2, const u16* __restrict__ h3,
    const u16* __restrict__ h4,
    const u16* __restrict__ W2f, const float* __restrict__ b2,
    const float* __restrict__ hx, const float* __restrict__ ubuf,
    float* __restrict__ out) {
  __shared__ u16 lx[BB * KPAD];
  int n = blockIdx.x;
  stage_mats((unsigned*)lx, n, i0, i1, i2, i3, i4, h0, h1, h2, h3, h4);
  __syncthreads();
  int lane = threadIdx.x & 63;
  int w = threadIdx.x >> 6;
  int Mtile = w & 1;
  int Nbase = (w >> 1) * 2;
  int colo = lane & 15;
  int quad = lane >> 4;
  float4v acc[2];
#pragma unroll
  for (int t = 0; t < 2; ++t) {
    float bv = b2[(Nbase + t) * 16 + colo];
    acc[t] = (float4v){bv, bv, bv, bv};
  }
  const u16* arow = &lx[(Mtile * 16 + colo) * KPAD];
  for (int ks = 0; ks < KSTEPS; ++ks) {
    short8 af = *(const short8*)(arow + ks * 32 + quad * 8);
#pragma unroll
    for (int t = 0; t < 2; ++t) {
      short8 bf = *(const short8*)(W2f + (size_t)(((Nbase + t) * KSTEPS + ks) * 64 + lane) * 8);
      acc[t] = __builtin_amdgcn_mfma_f32_16x16x32_bf16(af, bf, acc[t], 0, 0, 0);
    }
  }
  int brow0 = Mtile * 16 + quad * 4;
#pragma unroll
  for (int t = 0; t < 2; ++t) {
    int o = (Nbase + t) * 16 + colo;
#pragma unroll
    for (int r = 0; r < 4; ++r) {
      int b = brow0 + r;
      float c = tanhf_(acc[t][r]);
      float u = ubuf[(size_t)n * (BB * UU) + b * UU + o];
      float h = hx[(size_t)b * (NN * UU) + (size_t)n * UU + o];
      out[(size_t)b * (NN * UU) + (size_t)n * UU + o] = u * h + (1.0f - u) * c;
    }
  }
}

extern "C" void kernel_launch(void* const* d_in, const int* in_sizes, int n_in,
                              void* d_out, int out_size, void* d_ws, size_t ws_size,
                              hipStream_t stream) {
  const float* inp  = (const float*)d_in[0];
  const float* hx   = (const float*)d_in[1];
  const float* S0   = (const float*)d_in[2];
  const float* S1   = (const float*)d_in[3];
  const float* W    = (const float*)d_in[4];
  const float* bias = (const float*)d_in[5];
  const float* W2   = (const float*)d_in[6];
  const float* b2   = (const float*)d_in[7];
  float* out = (float*)d_out;

  char* ws = (char*)d_ws;
  const size_t XHB = (size_t)NN * XHC * sizeof(u16);
  const size_t XIB = (size_t)NN * XIC * sizeof(u16);
  u16* bufA = (u16*)(ws);              // xh0 -> xh'
  u16* bufB = (u16*)(ws + 1 * XHB);    // S0@x  (h)
  u16* bufC = (u16*)(ws + 2 * XHB);    // cheb0 (h)
  u16* bufD = (u16*)(ws + 3 * XHB);    // S1@x  (h)
  u16* bufE = (u16*)(ws + 4 * XHB);    // cheb1 (h)
  char* p = ws + 5 * XHB;
  u16* xi0 = (u16*)p;  p += XIB + 256;
  u16* yi1 = (u16*)p;  p += XIB + 256;
  u16* yi2 = (u16*)p;  p += XIB + 256;
  u16* yi3 = (u16*)p;  p += XIB + 256;
  u16* yi4 = (u16*)p;  p += XIB + 256;
  float* ubuf = (float*)p;             p += (size_t)NN * BB * UU * 4;
  int*   cols = (int*)p;               p += 2 * (size_t)NN * CAP * 4;
  float* vals = (float*)p;             p += 2 * (size_t)NN * CAP * 4;
  int*   nnzA = (int*)p;               p += 2 * (size_t)NN * 4;
  u16*   Wf   = (u16*)p;               p += (size_t)WF_G * 2;
  u16*   W2f  = (u16*)p;

  prep_w<<<(WF_G + WF_C + 255) / 256, 256, 0, stream>>>(W, W2, Wf, W2f);
  extract_csr<<<dim3(NN / 4, 2), 256, 0, stream>>>(S0, S1, cols, vals, nnzA);
  build_x0<<<NN, 256, 0, stream>>>(inp, hx, xi0, bufA);

  // gconv1: hop1 pair (shared source; xi tails compute S@xi once),
  //         cheb singles (one gather source per dispatch; xi cheb in tails)
  spmm_panel<<<dim3(10240, 2), 128, 0, stream>>>(cols, vals, nnzA,
      xi0, bufA, xi0, bufA, nullptr, nullptr, 1.f, 0.f, 0,
      yi1, bufB, yi3, bufD);
  spmm_panel<<<dim3(10240, 1), 128, 0, stream>>>(cols, vals, nnzA,
      yi1, bufB, yi1, bufB, xi0, bufA, 2.f, -1.f, 0,
      yi2, bufC, yi2, bufC);
  spmm_panel<<<dim3(10240, 1), 128, 0, stream>>>(cols, vals, nnzA,
      yi3, bufD, yi3, bufD, xi0, bufA, 2.f, -1.f, 1,
      yi4, bufE, yi4, bufE);

  // gate: writes xh' in place into bufA, u -> ubuf (yi1..yi4 preserved)
  gate_mfma<<<NN, 256, 0, stream>>>(xi0, yi1, yi2, yi3, yi4,
                                    bufA, bufB, bufC, bufD, bufE,
                                    Wf, bias, hx, bufA, ubuf);

  // gconv2 on x0' = (xi0, bufA); xi mats reused from gconv1 (no tails)
  spmm_panel<<<dim3(8192, 2), 128, 0, stream>>>(cols, vals, nnzA,
      xi0, bufA, xi0, bufA, nullptr, nullptr, 1.f, 0.f, 0,
      yi1, bufB, yi3, bufD);
  spmm_panel<<<dim3(8192, 1), 128, 0, stream>>>(cols, vals, nnzA,
      yi1, bufB, yi1, bufB, xi0, bufA, 2.f, -1.f, 0,
      yi2, bufC, yi2, bufC);
  spmm_panel<<<dim3(8192, 1), 128, 0, stream>>>(cols, vals, nnzA,
      yi3, bufD, yi3, bufD, xi0, bufA, 2.f, -1.f, 1,
      yi4, bufE, yi4, bufE);

  // candidate + final combine
  cand_mfma<<<NN, 256, 0, stream>>>(xi0, yi1, yi2, yi3, yi4,
                                    bufA, bufB, bufC, bufD, bufE,
                                    W2f, b2, hx, ubuf, out);
}

// Round 10
// 644.660 us; speedup vs baseline: 1.2307x; 1.2307x over previous
//
#include <hip/hip_runtime.h>
#include <math.h>

// DCGRU cell, N=4096, B=32, U=64, F=66, M=5, 2 supports.
// R10: (a) CHUNK 8->4: 8 KB LDS/wave -> 10 blocks/CU (R9 was 5, occupancy 19%
// -> latency exposed); (b) Chebyshev folded into weights (W0'=W0-W2-W4,
// W2'=2W2, W4'=2W4) so every SpMM is pure S@x — no z streams, no alpha/beta.
// Keeps: 1 KB panel DMA (global_load_lds size=16), bx&3 XCD pin, scalar CSR,
// xi tails + gconv2 xi reuse, MFMA gate/cand with B-fragment weights.

#define NN 4096
#define BB 32
#define UU 64
#define FF 66
#define MM 5
#define XHC 2048       // xh row elements (4096 B)
#define XIC 64         // xi row elements (128 B)
#define CAP 128        // max nnz/row, padded to %8 (min 16)
#define KPAD 360
#define KSTEPS 11
#define CHUNK 4
#define WF_G (8*11*64*8)
#define WF_C (4*11*64*8)

typedef unsigned short u16;
typedef __attribute__((ext_vector_type(8))) short short8;
typedef __attribute__((ext_vector_type(4))) float float4v;

__device__ __forceinline__ u16 f2bf(float f) {
  unsigned u = __float_as_uint(f);
  u += 0x7FFFu + ((u >> 16) & 1u);   // RNE
  return (u16)(u >> 16);
}
__device__ __forceinline__ unsigned pack2(float lo, float hi) {
  return (unsigned)f2bf(lo) | ((unsigned)f2bf(hi) << 16);
}
__device__ __forceinline__ float bflo(unsigned d) { return __uint_as_float(d << 16); }
__device__ __forceinline__ float bfhi(unsigned d) { return __uint_as_float(d & 0xFFFF0000u); }
__device__ __forceinline__ float bf1(u16 v) { return __uint_as_float((unsigned)v << 16); }

__device__ __forceinline__ float sigmoidf_(float x) {
  return 1.0f / (1.0f + __expf(-x));
}
__device__ __forceinline__ float tanhf_(float x) {
  x = fminf(fmaxf(x, -15.f), 15.f);
  float e = __expf(2.f * x);
  return (e - 1.f) / (e + 1.f);
}

// ---------------- CSR extraction: rows zero-padded to %8, min 16 ------------
__global__ __launch_bounds__(256) void extract_csr(
    const float* __restrict__ S0, const float* __restrict__ S1,
    int* __restrict__ cols, float* __restrict__ vals, int* __restrict__ nnz) {
  int wave = threadIdx.x >> 6;
  int lane = threadIdx.x & 63;
  int row  = blockIdx.x * 4 + wave;
  int sup  = blockIdx.y;
  const float* srow = (sup ? S1 : S0) + (size_t)row * NN;
  int*   crow = cols + ((size_t)sup * NN + row) * CAP;
  float* vrow = vals + ((size_t)sup * NN + row) * CAP;
  int base = 0;
  for (int j0 = 0; j0 < NN; j0 += 64) {
    float v = srow[j0 + lane];
    unsigned long long mask = __ballot(v != 0.0f);
    if (v != 0.0f) {
      int pos = base + __popcll(mask & ((1ull << lane) - 1ull));
      if (pos < CAP) { crow[pos] = j0 + lane; vrow[pos] = v; }
    }
    base += __popcll(mask);
  }
  if (base > CAP) base = CAP;
  int padded = (base + 7) & ~7;
  if (padded < 16) padded = 16;
  if (padded > CAP) padded = CAP;
  int p = base + lane;
  if (p < padded) { crow[p] = 0; vrow[p] = 0.0f; }
  if (lane == 0) nnz[sup * NN + row] = padded;
}

// ---------------- weight prep: Chebyshev fold + MFMA B-fragment order -------
// W'(m=0) = W0 - W2 - W4 ; W'(2) = 2*W2 ; W'(4) = 2*W4 ; W'(1,3) = W(1,3)
__device__ __forceinline__ float wfold(const float* W, int f, int m, int o, int O) {
  if (m == 0)
    return W[((size_t)f * MM + 0) * O + o] - W[((size_t)f * MM + 2) * O + o]
         - W[((size_t)f * MM + 4) * O + o];
  float v = W[((size_t)f * MM + m) * O + o];
  return (m == 2 || m == 4) ? 2.0f * v : v;
}
__global__ __launch_bounds__(256) void prep_w(
    const float* __restrict__ W, const float* __restrict__ W2,
    u16* __restrict__ Wf, u16* __restrict__ W2f) {
  int idx = blockIdx.x * 256 + threadIdx.x;
  if (idx < WF_G) {
    int j = idx & 7, lane = (idx >> 3) & 63, q = idx >> 9;
    int ks = q % 11, t = q / 11;
    int k = ks * 32 + (lane >> 4) * 8 + j, o = t * 16 + (lane & 15);
    float v = 0.f;
    if (k < 330) { int m = k / FF, f = k - m * FF; v = wfold(W, f, m, o, 128); }
    Wf[idx] = f2bf(v);
  } else if (idx < WF_G + WF_C) {
    int i2 = idx - WF_G;
    int j = i2 & 7, lane = (i2 >> 3) & 63, q = i2 >> 9;
    int ks = q % 11, t = q / 11;
    int k = ks * 32 + (lane >> 4) * 8 + j, o = t * 16 + (lane & 15);
    float v = 0.f;
    if (k < 330) { int m = k / FF, f = k - m * FF; v = wfold(W2, f, m, o, UU); }
    W2f[i2] = f2bf(v);
  }
}

// ---------------- build xi0 / xh0 -------------------------------------------
__global__ __launch_bounds__(256) void build_x0(
    const float* __restrict__ inp, const float* __restrict__ hx,
    u16* __restrict__ xi0, u16* __restrict__ xh0) {
  int n = blockIdx.x;
  unsigned* xhd = (unsigned*)(xh0 + (size_t)n * XHC);
  for (int j = threadIdx.x; j < XHC / 2; j += 256) {
    int b = j >> 5, f2 = (j & 31) * 2;
    const float* h = hx + (size_t)b * (NN * UU) + (size_t)n * UU + f2;
    xhd[j] = pack2(h[0], h[1]);
  }
  if (threadIdx.x < 32) {
    int b = threadIdx.x;
    unsigned* xid = (unsigned*)(xi0 + (size_t)n * XIC);
    xid[b] = pack2(inp[(size_t)b * (NN * 2) + n * 2],
                   inp[(size_t)b * (NN * 2) + n * 2 + 1]);
  }
}

// ---------------- SpMM: y = S@x. 4x1KB panels, 1 DMA/nnz, CHUNK=4 dbuf ------
__device__ __forceinline__ void fma8(float v, uint4 q, float* a) {
  a[0] = fmaf(v, bflo(q.x), a[0]); a[1] = fmaf(v, bfhi(q.x), a[1]);
  a[2] = fmaf(v, bflo(q.y), a[2]); a[3] = fmaf(v, bfhi(q.y), a[3]);
  a[4] = fmaf(v, bflo(q.z), a[4]); a[5] = fmaf(v, bfhi(q.z), a[5]);
  a[6] = fmaf(v, bflo(q.w), a[6]); a[7] = fmaf(v, bfhi(q.w), a[7]);
}

__device__ __forceinline__ void issueC(
    u16* buf, const int* crow, int k0, const u16* gpan, int lane) {
#pragma unroll
  for (int i = 0; i < CHUNK; ++i) {
    int c = crow[k0 + i];                               // scalar (s_load)
    const u16* g = gpan + ((size_t)c << 11) + (lane << 3);
    __builtin_amdgcn_global_load_lds(
        (const __attribute__((address_space(1))) void*)g,
        (__attribute__((address_space(3))) void*)(buf + i * 512), 16, 0, 0);
  }
}

__global__ __launch_bounds__(128) void spmm_panel(
    const int* __restrict__ cols, const float* __restrict__ vals,
    const int* __restrict__ nnz,
    const u16* xiA, const u16* xhA, const u16* xiB, const u16* xhB,
    int sup_base,
    u16* yiA, u16* yhA, u16* yiB, u16* yhB) {
  __shared__ u16 stage[2 * 2 * CHUNK * 512];   // 2 waves x 2 bufs x 4 KB
  int bx = blockIdx.x;
  int lane = threadIdx.x & 63;
  int wv = threadIdx.x >> 6;                   // 0..1
  int sup = sup_base + blockIdx.y;

  if (bx < 8192) {
    // ---- xh path ----
    int panel = bx & 3;
    int row = (bx >> 2) * 2 + wv;
    int srow = __builtin_amdgcn_readfirstlane(sup * NN + row);
    const u16* xh = blockIdx.y ? xhB : xhA;
    u16* yh = blockIdx.y ? yhB : yhA;
    const int*   crow = cols + (size_t)srow * CAP;
    const float* vrow = vals + (size_t)srow * CAP;
    int cnt = nnz[srow];                       // %8, >=16
    int nch = cnt >> 2;                        // >=4 chunks of 4
    u16* st = stage + wv * (2 * CHUNK * 512);
    const u16* gpan = xh + panel * 512;
    float a[8] = {0.f,0.f,0.f,0.f,0.f,0.f,0.f,0.f};

    issueC(st,               crow, 0,     gpan, lane);
    issueC(st + CHUNK * 512, crow, CHUNK, gpan, lane);
    float vv[CHUNK];
#pragma unroll
    for (int i = 0; i < CHUNK; ++i) vv[i] = vrow[i];

    for (int c = 0; c < nch; ++c) {
      float vvn[CHUNK];
      if (c + 1 < nch) {
#pragma unroll
        for (int i = 0; i < CHUNK; ++i) vvn[i] = vrow[(c + 1) * CHUNK + i];
      }
      if (c < nch - 1) asm volatile("s_waitcnt vmcnt(4)" ::: "memory");
      else             asm volatile("s_waitcnt vmcnt(0)" ::: "memory");
      u16* buf = st + (c & 1) * (CHUNK * 512);
#pragma unroll
      for (int i = 0; i < CHUNK; ++i) {
        uint4 q = *(const uint4*)(buf + i * 512 + lane * 8);
        fma8(vv[i], q, a);
      }
      if (c + 2 < nch) issueC(buf, crow, (c + 2) * CHUNK, gpan, lane);
#pragma unroll
      for (int i = 0; i < CHUNK; ++i) vv[i] = vvn[i];
    }

    size_t oh = (size_t)row * XHC + panel * 512 + lane * 8;
    uint4 o4;
    o4.x = pack2(a[0], a[1]); o4.y = pack2(a[2], a[3]);
    o4.z = pack2(a[4], a[5]); o4.w = pack2(a[6], a[7]);
    __builtin_nontemporal_store(o4.x, (unsigned*)(yh + oh));
    __builtin_nontemporal_store(o4.y, (unsigned*)(yh + oh) + 1);
    __builtin_nontemporal_store(o4.z, (unsigned*)(yh + oh) + 2);
    __builtin_nontemporal_store(o4.w, (unsigned*)(yh + oh) + 3);
  } else {
    // ---- xi path: one wave per row (128 B rows, register gather) ----
    int row = (bx - 8192) * 2 + wv;
    int srow = __builtin_amdgcn_readfirstlane(sup * NN + row);
    const u16* xs = blockIdx.y ? xiB : xiA;
    u16* yo = blockIdx.y ? yiB : yiA;
    const int*   crow = cols + (size_t)srow * CAP;
    const float* vrow = vals + (size_t)srow * CAP;
    int cnt = nnz[srow];
    float a = 0.f;
    for (int k0 = 0; k0 < cnt; k0 += 8) {
      int cc[8]; float vv[8];
#pragma unroll
      for (int i = 0; i < 8; ++i) { cc[i] = crow[k0 + i]; vv[i] = vrow[k0 + i]; }
      u16 q[8];
#pragma unroll
      for (int i = 0; i < 8; ++i) q[i] = xs[(size_t)cc[i] * XIC + lane];
#pragma unroll
      for (int i = 0; i < 8; ++i) a = fmaf(vv[i], bf1(q[i]), a);
    }
    yo[(size_t)row * XIC + lane] = f2bf(a);
  }
}

// ---------------- staging: 5 (xi,xh) mats -> lx[b][k=m*66+f], pad zeroed ----
__device__ __forceinline__ void stage_one(
    unsigned* lxd, int n, int m, const u16* xim, const u16* xhm) {
  const unsigned* sh = (const unsigned*)(xhm + (size_t)n * XHC);
  for (int j = threadIdx.x; j < XHC / 2; j += 256) {
    int b = j >> 5, f2d = j & 31;
    lxd[b * (KPAD / 2) + m * 33 + 1 + f2d] = sh[j];
  }
  if (threadIdx.x < 32) {
    const unsigned* si = (const unsigned*)(xim + (size_t)n * XIC);
    lxd[threadIdx.x * (KPAD / 2) + m * 33] = si[threadIdx.x];
  }
}
__device__ __forceinline__ void stage_mats(
    unsigned* lxd, int n,
    const u16* i0, const u16* i1, const u16* i2, const u16* i3, const u16* i4,
    const u16* h0, const u16* h1, const u16* h2, const u16* h3, const u16* h4) {
  stage_one(lxd, n, 0, i0, h0);
  stage_one(lxd, n, 1, i1, h1);
  stage_one(lxd, n, 2, i2, h2);
  stage_one(lxd, n, 3, i3, h3);
  stage_one(lxd, n, 4, i4, h4);
  for (int i = threadIdx.x; i < BB * 16; i += 256) {
    int b = i >> 4, d = i & 15;
    if (d < 15) lxd[b * (KPAD / 2) + 165 + d] = 0u;
  }
}

// ---------------- gate: sigmoid(x@W'+bias); r*hx -> xh' in place, u->ubuf ---
__global__ __launch_bounds__(256) void gate_mfma(
    const u16* i0, const u16* __restrict__ i1, const u16* __restrict__ i2,
    const u16* __restrict__ i3, const u16* __restrict__ i4,
    const u16* h0, const u16* __restrict__ h1, const u16* __restrict__ h2,
    const u16* __restrict__ h3, const u16* __restrict__ h4,
    const u16* __restrict__ Wf, const float* __restrict__ bias,
    const float* __restrict__ hx,
    u16* xhp, float* __restrict__ ubuf) {
  __shared__ u16 lx[BB * KPAD];
  __shared__ u16 lt[BB * UU];
  int n = blockIdx.x;
  stage_mats((unsigned*)lx, n, i0, i1, i2, i3, i4, h0, h1, h2, h3, h4);
  __syncthreads();
  int lane = threadIdx.x & 63;
  int w = threadIdx.x >> 6;
  int Mtile = w & 1;
  int Nbase = (w >> 1) * 4;
  int colo = lane & 15;
  int quad = lane >> 4;
  float4v acc[4];
#pragma unroll
  for (int t = 0; t < 4; ++t) {
    float bv = bias[(Nbase + t) * 16 + colo];
    acc[t] = (float4v){bv, bv, bv, bv};
  }
  const u16* arow = &lx[(Mtile * 16 + colo) * KPAD];
  for (int ks = 0; ks < KSTEPS; ++ks) {
    short8 af = *(const short8*)(arow + ks * 32 + quad * 8);
#pragma unroll
    for (int t = 0; t < 4; ++t) {
      short8 bf = *(const short8*)(Wf + (size_t)(((Nbase + t) * KSTEPS + ks) * 64 + lane) * 8);
      acc[t] = __builtin_amdgcn_mfma_f32_16x16x32_bf16(af, bf, acc[t], 0, 0, 0);
    }
  }
  int brow0 = Mtile * 16 + quad * 4;
#pragma unroll
  for (int t = 0; t < 4; ++t) {
    int o = (Nbase + t) * 16 + colo;
#pragma unroll
    for (int r = 0; r < 4; ++r) {
      int b = brow0 + r;
      float s = sigmoidf_(acc[t][r]);
      if (o < UU) {
        float h = hx[(size_t)b * (NN * UU) + (size_t)n * UU + o];
        lt[b * UU + o] = f2bf(s * h);
      } else {
        ubuf[(size_t)n * (BB * UU) + b * UU + (o - UU)] = s;
      }
    }
  }
  __syncthreads();
  unsigned* xrow = (unsigned*)(xhp + (size_t)n * XHC);
  const unsigned* ltd = (const unsigned*)lt;
  for (int j = threadIdx.x; j < XHC / 2; j += 256)
    xrow[j] = ltd[j];
}

// ---------------- candidate + final combine ---------------------------------
__global__ __launch_bounds__(256) void cand_mfma(
    const u16* __restrict__ i0, const u16* __restrict__ i1,
    const u16* __restrict__ i2, const u16* __restrict__ i3,
    const u16* __restrict__ i4,
    const u16* __restrict__ h0, const u16* __restrict__ h1,
    const u16* __restrict__ h2, const u16* __restrict__ h3,
    const u16* __restrict__ h4,
    const u16* __restrict__ W2f, const float* __restrict__ b2,
    const float* __restrict__ hx, const float* __restrict__ ubuf,
    float* __restrict__ out) {
  __shared__ u16 lx[BB * KPAD];
  int n = blockIdx.x;
  stage_mats((unsigned*)lx, n, i0, i1, i2, i3, i4, h0, h1, h2, h3, h4);
  __syncthreads();
  int lane = threadIdx.x & 63;
  int w = threadIdx.x >> 6;
  int Mtile = w & 1;
  int Nbase = (w >> 1) * 2;
  int colo = lane & 15;
  int quad = lane >> 4;
  float4v acc[2];
#pragma unroll
  for (int t = 0; t < 2; ++t) {
    float bv = b2[(Nbase + t) * 16 + colo];
    acc[t] = (float4v){bv, bv, bv, bv};
  }
  const u16* arow = &lx[(Mtile * 16 + colo) * KPAD];
  for (int ks = 0; ks < KSTEPS; ++ks) {
    short8 af = *(const short8*)(arow + ks * 32 + quad * 8);
#pragma unroll
    for (int t = 0; t < 2; ++t) {
      short8 bf = *(const short8*)(W2f + (size_t)(((Nbase + t) * KSTEPS + ks) * 64 + lane) * 8);
      acc[t] = __builtin_amdgcn_mfma_f32_16x16x32_bf16(af, bf, acc[t], 0, 0, 0);
    }
  }
  int brow0 = Mtile * 16 + quad * 4;
#pragma unroll
  for (int t = 0; t < 2; ++t) {
    int o = (Nbase + t) * 16 + colo;
#pragma unroll
    for (int r = 0; r < 4; ++r) {
      int b = brow0 + r;
      float c = tanhf_(acc[t][r]);
      float u = ubuf[(size_t)n * (BB * UU) + b * UU + o];
      float h = hx[(size_t)b * (NN * UU) + (size_t)n * UU + o];
      out[(size_t)b * (NN * UU) + (size_t)n * UU + o] = u * h + (1.0f - u) * c;
    }
  }
}

extern "C" void kernel_launch(void* const* d_in, const int* in_sizes, int n_in,
                              void* d_out, int out_size, void* d_ws, size_t ws_size,
                              hipStream_t stream) {
  const float* inp  = (const float*)d_in[0];
  const float* hx   = (const float*)d_in[1];
  const float* S0   = (const float*)d_in[2];
  const float* S1   = (const float*)d_in[3];
  const float* W    = (const float*)d_in[4];
  const float* bias = (const float*)d_in[5];
  const float* W2   = (const float*)d_in[6];
  const float* b2   = (const float*)d_in[7];
  float* out = (float*)d_out;

  char* ws = (char*)d_ws;
  const size_t XHB = (size_t)NN * XHC * sizeof(u16);
  const size_t XIB = (size_t)NN * XIC * sizeof(u16);
  u16* bufA = (u16*)(ws);              // xh0 -> xh'
  u16* bufB = (u16*)(ws + 1 * XHB);    // S0@x  (h)
  u16* bufC = (u16*)(ws + 2 * XHB);    // S0@S0@x (h)
  u16* bufD = (u16*)(ws + 3 * XHB);    // S1@x  (h)
  u16* bufE = (u16*)(ws + 4 * XHB);    // S1@S1@x (h)
  char* p = ws + 5 * XHB;
  u16* xi0 = (u16*)p;  p += XIB + 256;
  u16* yi1 = (u16*)p;  p += XIB + 256;
  u16* yi2 = (u16*)p;  p += XIB + 256;
  u16* yi3 = (u16*)p;  p += XIB + 256;
  u16* yi4 = (u16*)p;  p += XIB + 256;
  float* ubuf = (float*)p;             p += (size_t)NN * BB * UU * 4;
  int*   cols = (int*)p;               p += 2 * (size_t)NN * CAP * 4;
  float* vals = (float*)p;             p += 2 * (size_t)NN * CAP * 4;
  int*   nnzA = (int*)p;               p += 2 * (size_t)NN * 4;
  u16*   Wf   = (u16*)p;               p += (size_t)WF_G * 2;
  u16*   W2f  = (u16*)p;

  prep_w<<<(WF_G + WF_C + 255) / 256, 256, 0, stream>>>(W, W2, Wf, W2f);
  extract_csr<<<dim3(NN / 4, 2), 256, 0, stream>>>(S0, S1, cols, vals, nnzA);
  build_x0<<<NN, 256, 0, stream>>>(inp, hx, xi0, bufA);

  // gconv1: hop1 pair (shared source; xi tails), hop2 singles (pure S@x)
  spmm_panel<<<dim3(10240, 2), 128, 0, stream>>>(cols, vals, nnzA,
      xi0, bufA, xi0, bufA, 0, yi1, bufB, yi3, bufD);
  spmm_panel<<<dim3(10240, 1), 128, 0, stream>>>(cols, vals, nnzA,
      yi1, bufB, yi1, bufB, 0, yi2, bufC, yi2, bufC);
  spmm_panel<<<dim3(10240, 1), 128, 0, stream>>>(cols, vals, nnzA,
      yi3, bufD, yi3, bufD, 1, yi4, bufE, yi4, bufE);

  // gate: writes xh' in place into bufA, u -> ubuf (yi1..yi4 preserved)
  gate_mfma<<<NN, 256, 0, stream>>>(xi0, yi1, yi2, yi3, yi4,
                                    bufA, bufB, bufC, bufD, bufE,
                                    Wf, bias, hx, bufA, ubuf);

  // gconv2 on x0' = (xi0, bufA); xi mats reused from gconv1 (no tails)
  spmm_panel<<<dim3(8192, 2), 128, 0, stream>>>(cols, vals, nnzA,
      xi0, bufA, xi0, bufA, 0, yi1, bufB, yi3, bufD);
  spmm_panel<<<dim3(8192, 1), 128, 0, stream>>>(cols, vals, nnzA,
      yi1, bufB, yi1, bufB, 0, yi2, bufC, yi2, bufC);
  spmm_panel<<<dim3(8192, 1), 128, 0, stream>>>(cols, vals, nnzA,
      yi3, bufD, yi3, bufD, 1, yi4, bufE, yi4, bufE);

  // candidate + final combine
  cand_mfma<<<NN, 256, 0, stream>>>(xi0, yi1, yi2, yi3, yi4,
                                    bufA, bufB, bufC, bufD, bufE,
                                    W2f, b2, hx, ubuf, out);
}

// Round 11
// 609.167 us; speedup vs baseline: 1.3024x; 1.0583x over previous
//
#include <hip/hip_runtime.h>
#include <math.h>

// DCGRU cell, N=4096, B=32, U=64, F=66, M=5, 2 supports.
// R11: gate/cand MFMA read A-fragments DIRECTLY from global (k-scan = 5 mats
// x 2 halves of o in [0,64), + 1 xi kstep from prebuilt xiF buffer) — deletes
// the 21 KB/block LDS staging + barrier that made R10's gate 91.7 us at 5%
// MfmaUtil with 1.1M bank conflicts. Weights re-permuted to the new k order.
// xiF built once (xi diffusion shared by both gconvs). SpMM unchanged (R10).

#define NN 4096
#define BB 32
#define UU 64
#define FF 66
#define MM 5
#define XHC 2048       // xh row elements (4096 B)
#define XIC 64         // xi row elements (128 B)
#define CAP 128        // max nnz/row, padded to %8 (min 16)
#define CHUNK 4
#define WF_G (8*11*64*8)
#define WF_C (4*11*64*8)

typedef unsigned short u16;
typedef __attribute__((ext_vector_type(8))) short short8;
typedef __attribute__((ext_vector_type(4))) float float4v;

__device__ __forceinline__ u16 f2bf(float f) {
  unsigned u = __float_as_uint(f);
  u += 0x7FFFu + ((u >> 16) & 1u);   // RNE
  return (u16)(u >> 16);
}
__device__ __forceinline__ unsigned pack2(float lo, float hi) {
  return (unsigned)f2bf(lo) | ((unsigned)f2bf(hi) << 16);
}
__device__ __forceinline__ float bflo(unsigned d) { return __uint_as_float(d << 16); }
__device__ __forceinline__ float bfhi(unsigned d) { return __uint_as_float(d & 0xFFFF0000u); }
__device__ __forceinline__ float bf1(u16 v) { return __uint_as_float((unsigned)v << 16); }

__device__ __forceinline__ float sigmoidf_(float x) {
  return 1.0f / (1.0f + __expf(-x));
}
__device__ __forceinline__ float tanhf_(float x) {
  x = fminf(fmaxf(x, -15.f), 15.f);
  float e = __expf(2.f * x);
  return (e - 1.f) / (e + 1.f);
}

// ---------------- CSR extraction: rows zero-padded to %8, min 16 ------------
__global__ __launch_bounds__(256) void extract_csr(
    const float* __restrict__ S0, const float* __restrict__ S1,
    int* __restrict__ cols, float* __restrict__ vals, int* __restrict__ nnz) {
  int wave = threadIdx.x >> 6;
  int lane = threadIdx.x & 63;
  int row  = blockIdx.x * 4 + wave;
  int sup  = blockIdx.y;
  const float* srow = (sup ? S1 : S0) + (size_t)row * NN;
  int*   crow = cols + ((size_t)sup * NN + row) * CAP;
  float* vrow = vals + ((size_t)sup * NN + row) * CAP;
  int base = 0;
  for (int j0 = 0; j0 < NN; j0 += 64) {
    float v = srow[j0 + lane];
    unsigned long long mask = __ballot(v != 0.0f);
    if (v != 0.0f) {
      int pos = base + __popcll(mask & ((1ull << lane) - 1ull));
      if (pos < CAP) { crow[pos] = j0 + lane; vrow[pos] = v; }
    }
    base += __popcll(mask);
  }
  if (base > CAP) base = CAP;
  int padded = (base + 7) & ~7;
  if (padded < 16) padded = 16;
  if (padded > CAP) padded = CAP;
  int p = base + lane;
  if (p < padded) { crow[p] = 0; vrow[p] = 0.0f; }
  if (lane == 0) nnz[sup * NN + row] = padded;
}

// ---------------- weight prep: Chebyshev fold + NEW k-scan fragment order ---
// k-scan: ks in [0,10): m=ks>>1, h=ks&1, covers f = 2 + h*32 + qj (qj=0..31).
//         ks == 10:    qj<10 -> m=qj>>1, f=qj&1 ; else zero (xi kstep).
// W'(m=0) = W0 - W2 - W4 ; W'(2) = 2*W2 ; W'(4) = 2*W4 ; W'(1,3) unchanged.
__device__ __forceinline__ float wfold(const float* W, int f, int m, int o, int O) {
  if (m == 0)
    return W[((size_t)f * MM + 0) * O + o] - W[((size_t)f * MM + 2) * O + o]
         - W[((size_t)f * MM + 4) * O + o];
  float v = W[((size_t)f * MM + m) * O + o];
  return (m == 2 || m == 4) ? 2.0f * v : v;
}
__global__ __launch_bounds__(256) void prep_w(
    const float* __restrict__ W, const float* __restrict__ W2,
    u16* __restrict__ Wf, u16* __restrict__ W2f) {
  int idx = blockIdx.x * 256 + threadIdx.x;
  if (idx < WF_G) {
    int j = idx & 7, lane = (idx >> 3) & 63, q = idx >> 9;
    int ks = q % 11, t = q / 11;
    int o = t * 16 + (lane & 15);
    int qj = (lane >> 4) * 8 + j;
    float v = 0.f;
    if (ks < 10)      { v = wfold(W, 2 + (ks & 1) * 32 + qj, ks >> 1, o, 128); }
    else if (qj < 10) { v = wfold(W, qj & 1, qj >> 1, o, 128); }
    Wf[idx] = f2bf(v);
  } else if (idx < WF_G + WF_C) {
    int i2 = idx - WF_G;
    int j = i2 & 7, lane = (i2 >> 3) & 63, q = i2 >> 9;
    int ks = q % 11, t = q / 11;
    int o = t * 16 + (lane & 15);
    int qj = (lane >> 4) * 8 + j;
    float v = 0.f;
    if (ks < 10)      { v = wfold(W2, 2 + (ks & 1) * 32 + qj, ks >> 1, o, UU); }
    else if (qj < 10) { v = wfold(W2, qj & 1, qj >> 1, o, UU); }
    W2f[i2] = f2bf(v);
  }
}

// ---------------- build xi0 / xh0 -------------------------------------------
__global__ __launch_bounds__(256) void build_x0(
    const float* __restrict__ inp, const float* __restrict__ hx,
    u16* __restrict__ xi0, u16* __restrict__ xh0) {
  int n = blockIdx.x;
  unsigned* xhd = (unsigned*)(xh0 + (size_t)n * XHC);
  for (int j = threadIdx.x; j < XHC / 2; j += 256) {
    int b = j >> 5, f2 = (j & 31) * 2;
    const float* h = hx + (size_t)b * (NN * UU) + (size_t)n * UU + f2;
    xhd[j] = pack2(h[0], h[1]);
  }
  if (threadIdx.x < 32) {
    int b = threadIdx.x;
    unsigned* xid = (unsigned*)(xi0 + (size_t)n * XIC);
    xid[b] = pack2(inp[(size_t)b * (NN * 2) + n * 2],
                   inp[(size_t)b * (NN * 2) + n * 2 + 1]);
  }
}

// ---------------- xiF: xi mats packed in A-fragment order -------------------
// xiF[n][b*32 + (m*2+f)] = xi_m[n][b*2+f], zero-padded to 32 k's.
__global__ __launch_bounds__(256) void build_xif(
    const u16* __restrict__ x0, const u16* __restrict__ y1,
    const u16* __restrict__ y2, const u16* __restrict__ y3,
    const u16* __restrict__ y4, unsigned* __restrict__ xiF) {
  int n = blockIdx.x;
  const unsigned* rows[5] = {
    (const unsigned*)(x0 + (size_t)n * XIC), (const unsigned*)(y1 + (size_t)n * XIC),
    (const unsigned*)(y2 + (size_t)n * XIC), (const unsigned*)(y3 + (size_t)n * XIC),
    (const unsigned*)(y4 + (size_t)n * XIC)};
  unsigned* o = xiF + (size_t)n * 512;
  for (int idx = threadIdx.x; idx < 512; idx += 256) {
    int b = idx >> 4, jd = idx & 15;
    o[idx] = (jd < 5) ? rows[jd][b] : 0u;
  }
}

// ---------------- SpMM: y = S@x. 4x1KB panels, 1 DMA/nnz, CHUNK=4 dbuf ------
__device__ __forceinline__ void fma8(float v, uint4 q, float* a) {
  a[0] = fmaf(v, bflo(q.x), a[0]); a[1] = fmaf(v, bfhi(q.x), a[1]);
  a[2] = fmaf(v, bflo(q.y), a[2]); a[3] = fmaf(v, bfhi(q.y), a[3]);
  a[4] = fmaf(v, bflo(q.z), a[4]); a[5] = fmaf(v, bfhi(q.z), a[5]);
  a[6] = fmaf(v, bflo(q.w), a[6]); a[7] = fmaf(v, bfhi(q.w), a[7]);
}

__device__ __forceinline__ void issueC(
    u16* buf, const int* crow, int k0, const u16* gpan, int lane) {
#pragma unroll
  for (int i = 0; i < CHUNK; ++i) {
    int c = crow[k0 + i];                               // scalar (s_load)
    const u16* g = gpan + ((size_t)c << 11) + (lane << 3);
    __builtin_amdgcn_global_load_lds(
        (const __attribute__((address_space(1))) void*)g,
        (__attribute__((address_space(3))) void*)(buf + i * 512), 16, 0, 0);
  }
}

__global__ __launch_bounds__(128) void spmm_panel(
    const int* __restrict__ cols, const float* __restrict__ vals,
    const int* __restrict__ nnz,
    const u16* xiA, const u16* xhA, const u16* xiB, const u16* xhB,
    int sup_base,
    u16* yiA, u16* yhA, u16* yiB, u16* yhB) {
  __shared__ u16 stage[2 * 2 * CHUNK * 512];   // 2 waves x 2 bufs x 4 KB
  int bx = blockIdx.x;
  int lane = threadIdx.x & 63;
  int wv = threadIdx.x >> 6;
  int sup = sup_base + blockIdx.y;

  if (bx < 8192) {
    int panel = bx & 3;
    int row = (bx >> 2) * 2 + wv;
    int srow = __builtin_amdgcn_readfirstlane(sup * NN + row);
    const u16* xh = blockIdx.y ? xhB : xhA;
    u16* yh = blockIdx.y ? yhB : yhA;
    const int*   crow = cols + (size_t)srow * CAP;
    const float* vrow = vals + (size_t)srow * CAP;
    int cnt = nnz[srow];
    int nch = cnt >> 2;
    u16* st = stage + wv * (2 * CHUNK * 512);
    const u16* gpan = xh + panel * 512;
    float a[8] = {0.f,0.f,0.f,0.f,0.f,0.f,0.f,0.f};

    issueC(st,               crow, 0,     gpan, lane);
    issueC(st + CHUNK * 512, crow, CHUNK, gpan, lane);
    float vv[CHUNK];
#pragma unroll
    for (int i = 0; i < CHUNK; ++i) vv[i] = vrow[i];

    for (int c = 0; c < nch; ++c) {
      float vvn[CHUNK];
      if (c + 1 < nch) {
#pragma unroll
        for (int i = 0; i < CHUNK; ++i) vvn[i] = vrow[(c + 1) * CHUNK + i];
      }
      if (c < nch - 1) asm volatile("s_waitcnt vmcnt(4)" ::: "memory");
      else             asm volatile("s_waitcnt vmcnt(0)" ::: "memory");
      u16* buf = st + (c & 1) * (CHUNK * 512);
#pragma unroll
      for (int i = 0; i < CHUNK; ++i) {
        uint4 q = *(const uint4*)(buf + i * 512 + lane * 8);
        fma8(vv[i], q, a);
      }
      if (c + 2 < nch) issueC(buf, crow, (c + 2) * CHUNK, gpan, lane);
#pragma unroll
      for (int i = 0; i < CHUNK; ++i) vv[i] = vvn[i];
    }

    size_t oh = (size_t)row * XHC + panel * 512 + lane * 8;
    uint4 o4;
    o4.x = pack2(a[0], a[1]); o4.y = pack2(a[2], a[3]);
    o4.z = pack2(a[4], a[5]); o4.w = pack2(a[6], a[7]);
    __builtin_nontemporal_store(o4.x, (unsigned*)(yh + oh));
    __builtin_nontemporal_store(o4.y, (unsigned*)(yh + oh) + 1);
    __builtin_nontemporal_store(o4.z, (unsigned*)(yh + oh) + 2);
    __builtin_nontemporal_store(o4.w, (unsigned*)(yh + oh) + 3);
  } else {
    int row = (bx - 8192) * 2 + wv;
    int srow = __builtin_amdgcn_readfirstlane(sup * NN + row);
    const u16* xs = blockIdx.y ? xiB : xiA;
    u16* yo = blockIdx.y ? yiB : yiA;
    const int*   crow = cols + (size_t)srow * CAP;
    const float* vrow = vals + (size_t)srow * CAP;
    int cnt = nnz[srow];
    float a = 0.f;
    for (int k0 = 0; k0 < cnt; k0 += 8) {
      int cc[8]; float vv[8];
#pragma unroll
      for (int i = 0; i < 8; ++i) { cc[i] = crow[k0 + i]; vv[i] = vrow[k0 + i]; }
      u16 q[8];
#pragma unroll
      for (int i = 0; i < 8; ++i) q[i] = xs[(size_t)cc[i] * XIC + lane];
#pragma unroll
      for (int i = 0; i < 8; ++i) a = fmaf(vv[i], bf1(q[i]), a);
    }
    yo[(size_t)row * XIC + lane] = f2bf(a);
  }
}

// ---------------- gate: direct-A MFMA; r*hx -> xh' in place, u -> ubuf ------
__global__ __launch_bounds__(256) void gate_mfma(
    const u16* __restrict__ xiF,
    const u16* h0, const u16* __restrict__ h1, const u16* __restrict__ h2,
    const u16* __restrict__ h3, const u16* __restrict__ h4,
    const u16* __restrict__ Wf, const float* __restrict__ bias,
    const float* __restrict__ hx,
    u16* xhp, float* __restrict__ ubuf) {
  __shared__ u16 lt[BB * UU];           // r*hx staging for coalesced writeback
  int n = blockIdx.x;
  int lane = threadIdx.x & 63;
  int w = threadIdx.x >> 6;
  int Mtile = w & 1;
  int Nbase = (w >> 1) * 4;
  int colo = lane & 15;
  int quad = lane >> 4;
  const u16* hm[5] = {h0, h1, h2, h3, h4};
  float4v acc[4];
#pragma unroll
  for (int t = 0; t < 4; ++t) {
    float bv = bias[(Nbase + t) * 16 + colo];
    acc[t] = (float4v){bv, bv, bv, bv};
  }
  int aoff = (Mtile * 16 + colo) * 64 + quad * 8;  // within an xh row
#pragma unroll
  for (int ks = 0; ks < 10; ++ks) {
    short8 af = *(const short8*)(hm[ks >> 1] + (size_t)n * XHC + aoff + (ks & 1) * 32);
#pragma unroll
    for (int t = 0; t < 4; ++t) {
      short8 bf = *(const short8*)(Wf + (size_t)(((Nbase + t) * 11 + ks) * 64 + lane) * 8);
      acc[t] = __builtin_amdgcn_mfma_f32_16x16x32_bf16(af, bf, acc[t], 0, 0, 0);
    }
  }
  {
    short8 af = *(const short8*)(xiF + (size_t)n * 1024 + (Mtile * 16 + colo) * 32 + quad * 8);
#pragma unroll
    for (int t = 0; t < 4; ++t) {
      short8 bf = *(const short8*)(Wf + (size_t)(((Nbase + t) * 11 + 10) * 64 + lane) * 8);
      acc[t] = __builtin_amdgcn_mfma_f32_16x16x32_bf16(af, bf, acc[t], 0, 0, 0);
    }
  }
  int brow0 = Mtile * 16 + quad * 4;
#pragma unroll
  for (int t = 0; t < 4; ++t) {
    int o = (Nbase + t) * 16 + colo;
#pragma unroll
    for (int r = 0; r < 4; ++r) {
      int b = brow0 + r;
      float s = sigmoidf_(acc[t][r]);
      if (o < UU) {
        float h = hx[(size_t)b * (NN * UU) + (size_t)n * UU + o];
        lt[b * UU + o] = f2bf(s * h);
      } else {
        ubuf[(size_t)n * (BB * UU) + b * UU + (o - UU)] = s;
      }
    }
  }
  __syncthreads();
  unsigned* xrow = (unsigned*)(xhp + (size_t)n * XHC);
  const unsigned* ltd = (const unsigned*)lt;
  for (int j = threadIdx.x; j < XHC / 2; j += 256)
    xrow[j] = ltd[j];
}

// ---------------- candidate + final combine (no LDS at all) -----------------
__global__ __launch_bounds__(256) void cand_mfma(
    const u16* __restrict__ xiF,
    const u16* __restrict__ h0, const u16* __restrict__ h1,
    const u16* __restrict__ h2, const u16* __restrict__ h3,
    const u16* __restrict__ h4,
    const u16* __restrict__ W2f, const float* __restrict__ b2,
    const float* __restrict__ hx, const float* __restrict__ ubuf,
    float* __restrict__ out) {
  int n = blockIdx.x;
  int lane = threadIdx.x & 63;
  int w = threadIdx.x >> 6;
  int Mtile = w & 1;
  int Nbase = (w >> 1) * 2;
  int colo = lane & 15;
  int quad = lane >> 4;
  const u16* hm[5] = {h0, h1, h2, h3, h4};
  float4v acc[2];
#pragma unroll
  for (int t = 0; t < 2; ++t) {
    float bv = b2[(Nbase + t) * 16 + colo];
    acc[t] = (float4v){bv, bv, bv, bv};
  }
  int aoff = (Mtile * 16 + colo) * 64 + quad * 8;
#pragma unroll
  for (int ks = 0; ks < 10; ++ks) {
    short8 af = *(const short8*)(hm[ks >> 1] + (size_t)n * XHC + aoff + (ks & 1) * 32);
#pragma unroll
    for (int t = 0; t < 2; ++t) {
      short8 bf = *(const short8*)(W2f + (size_t)(((Nbase + t) * 11 + ks) * 64 + lane) * 8);
      acc[t] = __builtin_amdgcn_mfma_f32_16x16x32_bf16(af, bf, acc[t], 0, 0, 0);
    }
  }
  {
    short8 af = *(const short8*)(xiF + (size_t)n * 1024 + (Mtile * 16 + colo) * 32 + quad * 8);
#pragma unroll
    for (int t = 0; t < 2; ++t) {
      short8 bf = *(const short8*)(W2f + (size_t)(((Nbase + t) * 11 + 10) * 64 + lane) * 8);
      acc[t] = __builtin_amdgcn_mfma_f32_16x16x32_bf16(af, bf, acc[t], 0, 0, 0);
    }
  }
  int brow0 = Mtile * 16 + quad * 4;
#pragma unroll
  for (int t = 0; t < 2; ++t) {
    int o = (Nbase + t) * 16 + colo;
#pragma unroll
    for (int r = 0; r < 4; ++r) {
      int b = brow0 + r;
      float c = tanhf_(acc[t][r]);
      float u = ubuf[(size_t)n * (BB * UU) + b * UU + o];
      float h = hx[(size_t)b * (NN * UU) + (size_t)n * UU + o];
      out[(size_t)b * (NN * UU) + (size_t)n * UU + o] = u * h + (1.0f - u) * c;
    }
  }
}

extern "C" void kernel_launch(void* const* d_in, const int* in_sizes, int n_in,
                              void* d_out, int out_size, void* d_ws, size_t ws_size,
                              hipStream_t stream) {
  const float* inp  = (const float*)d_in[0];
  const float* hx   = (const float*)d_in[1];
  const float* S0   = (const float*)d_in[2];
  const float* S1   = (const float*)d_in[3];
  const float* W    = (const float*)d_in[4];
  const float* bias = (const float*)d_in[5];
  const float* W2   = (const float*)d_in[6];
  const float* b2   = (const float*)d_in[7];
  float* out = (float*)d_out;

  char* ws = (char*)d_ws;
  const size_t XHB = (size_t)NN * XHC * sizeof(u16);
  const size_t XIB = (size_t)NN * XIC * sizeof(u16);
  u16* bufA = (u16*)(ws);              // xh0 -> xh'
  u16* bufB = (u16*)(ws + 1 * XHB);    // S0@x
  u16* bufC = (u16*)(ws + 2 * XHB);    // S0@S0@x
  u16* bufD = (u16*)(ws + 3 * XHB);    // S1@x
  u16* bufE = (u16*)(ws + 4 * XHB);    // S1@S1@x
  char* p = ws + 5 * XHB;
  u16* xi0 = (u16*)p;  p += XIB + 256;
  u16* yi1 = (u16*)p;  p += XIB + 256;
  u16* yi2 = (u16*)p;  p += XIB + 256;
  u16* yi3 = (u16*)p;  p += XIB + 256;
  u16* yi4 = (u16*)p;  p += XIB + 256;
  float* ubuf = (float*)p;             p += (size_t)NN * BB * UU * 4;
  int*   cols = (int*)p;               p += 2 * (size_t)NN * CAP * 4;
  float* vals = (float*)p;             p += 2 * (size_t)NN * CAP * 4;
  int*   nnzA = (int*)p;               p += 2 * (size_t)NN * 4;
  u16*   Wf   = (u16*)p;               p += (size_t)WF_G * 2;
  u16*   W2f  = (u16*)p;               p += (size_t)WF_C * 2;
  u16*   xiF  = (u16*)p;               // NN * 1024 u16 = 8 MB

  prep_w<<<(WF_G + WF_C + 255) / 256, 256, 0, stream>>>(W, W2, Wf, W2f);
  extract_csr<<<dim3(NN / 4, 2), 256, 0, stream>>>(S0, S1, cols, vals, nnzA);
  build_x0<<<NN, 256, 0, stream>>>(inp, hx, xi0, bufA);

  // gconv1: hop1 pair (shared source; xi tails), hop2 singles (pure S@x)
  spmm_panel<<<dim3(10240, 2), 128, 0, stream>>>(cols, vals, nnzA,
      xi0, bufA, xi0, bufA, 0, yi1, bufB, yi3, bufD);
  spmm_panel<<<dim3(10240, 1), 128, 0, stream>>>(cols, vals, nnzA,
      yi1, bufB, yi1, bufB, 0, yi2, bufC, yi2, bufC);
  spmm_panel<<<dim3(10240, 1), 128, 0, stream>>>(cols, vals, nnzA,
      yi3, bufD, yi3, bufD, 1, yi4, bufE, yi4, bufE);

  // xi mats final for both gconvs -> pack once in A-fragment order
  build_xif<<<NN, 256, 0, stream>>>(xi0, yi1, yi2, yi3, yi4, (unsigned*)xiF);

  // gate: writes xh' in place into bufA, u -> ubuf
  gate_mfma<<<NN, 256, 0, stream>>>(xiF, bufA, bufB, bufC, bufD, bufE,
                                    Wf, bias, hx, bufA, ubuf);

  // gconv2 on x0' = (xiF-part unchanged, bufA); xh path only
  spmm_panel<<<dim3(8192, 2), 128, 0, stream>>>(cols, vals, nnzA,
      xi0, bufA, xi0, bufA, 0, yi1, bufB, yi3, bufD);
  spmm_panel<<<dim3(8192, 1), 128, 0, stream>>>(cols, vals, nnzA,
      yi1, bufB, yi1, bufB, 0, yi2, bufC, yi2, bufC);
  spmm_panel<<<dim3(8192, 1), 128, 0, stream>>>(cols, vals, nnzA,
      yi3, bufD, yi3, bufD, 1, yi4, bufE, yi4, bufE);

  // candidate + final combine
  cand_mfma<<<NN, 256, 0, stream>>>(xiF, bufA, bufB, bufC, bufD, bufE,
                                    W2f, b2, hx, ubuf, out);
}